// Round 1
// baseline (527.072 us; speedup 1.0000x reference)
//
#include <hip/hip_runtime.h>

// Problem constants (fixed by the reference)
#define KS   5      // kernel size
#define DIL  2      // dilation
#define PAD  4      // (KS/2)*DIL
#define B_   4
#define C_   32
#define P_   8
#define OUTC 24     // DYNAMIC_SIZE — only first 24 channels are output
#define H_   512
#define W_   512
#define HW   (H_ * W_)

__global__ __launch_bounds__(256)
void bilateral_kernel(const float* __restrict__ inp,   // (B, C, H, W)
                      const float* __restrict__ par,   // (B, P, H, W)
                      float* __restrict__ out)         // (B, OUTC, H, W)
{
    const int tid = blockIdx.x * blockDim.x + threadIdx.x;
    // one thread per pixel; grid covers exactly B*H*W
    const int x = tid & (W_ - 1);
    const int y = (tid >> 9) & (H_ - 1);
    const int b = tid >> 18;

    const float* __restrict__ parb = par + (size_t)b * P_ * HW;
    const float* __restrict__ inpb = inp + (size_t)b * C_ * HW;
    float* __restrict__ outb       = out + (size_t)b * OUTC * HW;

    const int cidx = y * W_ + x;

    // center params (8 guide channels)
    float pc[P_];
#pragma unroll
    for (int p = 0; p < P_; ++p) pc[p] = parb[p * HW + cidx];

    // 25 range weights + neighbor offsets
    float w[KS * KS];
    int   noff[KS * KS];
    float wsum = 0.f;
#pragma unroll
    for (int dy = 0; dy < KS; ++dy) {
#pragma unroll
        for (int dx = 0; dx < KS; ++dx) {
            const int yy = y + dy * DIL - PAD;
            const int xx = x + dx * DIL - PAD;
            const bool valid = (yy >= 0) & (yy < H_) & (xx >= 0) & (xx < W_);
            // clamp so OOB lanes still load in-bounds memory; weight forced to 0
            const int yyc = min(max(yy, 0), H_ - 1);
            const int xxc = min(max(xx, 0), W_ - 1);
            const int nidx = yyc * W_ + xxc;
            float d2 = 0.f;
#pragma unroll
            for (int p = 0; p < P_; ++p) {
                const float d = pc[p] - parb[p * HW + nidx];
                d2 += d * d;
            }
            const float ww = valid ? __expf(-d2) : 0.f;
            w[dy * KS + dx]    = ww;
            noff[dy * KS + dx] = nidx;
            wsum += ww;
        }
    }

    // normalize weights once (center tap has w=1, so wsum >= 1)
    const float inv = 1.f / (wsum + 1e-8f);
#pragma unroll
    for (int t = 0; t < KS * KS; ++t) w[t] *= inv;

    // weighted gather for the 24 output channels
    for (int c = 0; c < OUTC; ++c) {
        const float* __restrict__ ic = inpb + c * HW;
        float acc = 0.f;
#pragma unroll
        for (int t = 0; t < KS * KS; ++t) {
            acc += w[t] * ic[noff[t]];
        }
        outb[c * HW + cidx] = acc;
    }
}

extern "C" void kernel_launch(void* const* d_in, const int* in_sizes, int n_in,
                              void* d_out, int out_size, void* d_ws, size_t ws_size,
                              hipStream_t stream) {
    const float* inp = (const float*)d_in[0];   // (4,32,512,512) fp32
    const float* par = (const float*)d_in[1];   // (4,8,512,512) fp32
    float* out = (float*)d_out;                 // (4,24,512,512) fp32

    const int total = B_ * H_ * W_;             // 1,048,576 pixels
    dim3 block(256);
    dim3 grid(total / 256);                     // 4096 blocks, exact cover
    bilateral_kernel<<<grid, block, 0, stream>>>(inp, par, out);
}

// Round 2
// 487.829 us; speedup vs baseline: 1.0804x; 1.0804x over previous
//
#include <hip/hip_runtime.h>

// Problem constants (fixed by the reference)
#define KS   5      // kernel size
#define DIL  2      // dilation
#define PAD  4      // (KS/2)*DIL
#define B_   4
#define C_   32
#define P_   8
#define OUTC 24     // DYNAMIC_SIZE
#define H_   512
#define W_   512
#define HW   (H_ * W_)
#define GPR  128    // 4-pixel groups per row (512/4)

typedef float4 f4;

// Each thread computes 4 consecutive x-pixels (one float4 of output per channel).
// Dilation=2 => all 5 dx taps for the 4-pixel group live in the 12-float row
// segment [x0-4, x0+7], loaded as 3 aligned float4 chunks per (channel, dy).
__global__ __launch_bounds__(256)
void bilateral4(const float* __restrict__ inp,   // (B, C, H, W)
                const float* __restrict__ par,   // (B, P, H, W)
                float* __restrict__ out)         // (B, OUTC, H, W)
{
    const int tid = blockIdx.x * blockDim.x + threadIdx.x;
    const int g  = tid & (GPR - 1);
    const int y  = (tid >> 7) & (H_ - 1);
    const int b  = tid >> 16;              // GPR*H_ = 65536 = 2^16 per batch
    const int x0 = g << 2;

    const float* __restrict__ parb = par + (size_t)b * P_ * HW;
    const float* __restrict__ inpb = inp + (size_t)b * C_ * HW;
    float* __restrict__ outb       = out + (size_t)b * OUTC * HW;

    // per-dy clamped row offsets + validity
    int  rowoff[KS];
    bool rowok[KS];
#pragma unroll
    for (int d = 0; d < KS; ++d) {
        const int yy = y + d * DIL - PAD;
        rowok[d]  = (yy >= 0) & (yy < H_);
        const int yyc = min(max(yy, 0), H_ - 1);
        rowoff[d] = yyc * W_;
    }
    // 3 chunk x-bases (4-aligned). OOB chunks are ENTIRELY out of the row,
    // and feed only zero-weight (masked) taps, so clamping the address is safe.
    int cbx[3];
#pragma unroll
    for (int k = 0; k < 3; ++k) {
        const int xx = x0 + 4 * (k - 1);
        cbx[k] = min(max(xx, 0), W_ - 4);
    }

    // ---- weight phase: accumulate d2 over the 8 guide channels ----
    f4 d2[KS * KS];
#pragma unroll
    for (int t = 0; t < KS * KS; ++t) d2[t] = make_float4(0.f, 0.f, 0.f, 0.f);

#pragma unroll
    for (int p = 0; p < P_; ++p) {
        const float* __restrict__ pp = parb + p * HW;
        const f4 pc = *(const f4*)(pp + y * W_ + x0);    // center params, 4 px
#pragma unroll
        for (int d = 0; d < KS; ++d) {
            float r[12];
#pragma unroll
            for (int k = 0; k < 3; ++k) {
                const f4 v = *(const f4*)(pp + rowoff[d] + cbx[k]);
                r[4 * k + 0] = v.x; r[4 * k + 1] = v.y;
                r[4 * k + 2] = v.z; r[4 * k + 3] = v.w;
            }
#pragma unroll
            for (int e = 0; e < KS; ++e) {
                f4& a = d2[d * KS + e];
                const float dx0 = pc.x - r[0 + 2 * e];
                const float dx1 = pc.y - r[1 + 2 * e];
                const float dx2 = pc.z - r[2 + 2 * e];
                const float dx3 = pc.w - r[3 + 2 * e];
                a.x += dx0 * dx0; a.y += dx1 * dx1;
                a.z += dx2 * dx2; a.w += dx3 * dx3;
            }
        }
    }

    // ---- exp + mask + normalize ----
    // x-validity per (dx-tap e, pixel i): xx = x0 + i + 2e - 4 in [0, W)
    f4 w[KS * KS];
    f4 wsum = make_float4(0.f, 0.f, 0.f, 0.f);
#pragma unroll
    for (int d = 0; d < KS; ++d) {
#pragma unroll
        for (int e = 0; e < KS; ++e) {
            const int t = d * KS + e;
            f4 ww;
            {
                const int xb = x0 + e * DIL - PAD;
                const float m0 = (rowok[d] & (xb + 0 >= 0) & (xb + 0 < W_)) ? 1.f : 0.f;
                const float m1 = (rowok[d] & (xb + 1 >= 0) & (xb + 1 < W_)) ? 1.f : 0.f;
                const float m2 = (rowok[d] & (xb + 2 >= 0) & (xb + 2 < W_)) ? 1.f : 0.f;
                const float m3 = (rowok[d] & (xb + 3 >= 0) & (xb + 3 < W_)) ? 1.f : 0.f;
                ww.x = m0 * __expf(-d2[t].x);
                ww.y = m1 * __expf(-d2[t].y);
                ww.z = m2 * __expf(-d2[t].z);
                ww.w = m3 * __expf(-d2[t].w);
            }
            w[t] = ww;
            wsum.x += ww.x; wsum.y += ww.y; wsum.z += ww.z; wsum.w += ww.w;
        }
    }
    const f4 inv = make_float4(1.f / (wsum.x + 1e-8f), 1.f / (wsum.y + 1e-8f),
                               1.f / (wsum.z + 1e-8f), 1.f / (wsum.w + 1e-8f));
#pragma unroll
    for (int t = 0; t < KS * KS; ++t) {
        w[t].x *= inv.x; w[t].y *= inv.y; w[t].z *= inv.z; w[t].w *= inv.w;
    }

    // ---- channel loop: 3 float4 loads per (c, dy), 25 taps from registers ----
    const int obase = y * W_ + x0;
    for (int c = 0; c < OUTC; ++c) {
        const float* __restrict__ ic = inpb + c * HW;
        f4 acc = make_float4(0.f, 0.f, 0.f, 0.f);
#pragma unroll
        for (int d = 0; d < KS; ++d) {
            float r[12];
#pragma unroll
            for (int k = 0; k < 3; ++k) {
                const f4 v = *(const f4*)(ic + rowoff[d] + cbx[k]);
                r[4 * k + 0] = v.x; r[4 * k + 1] = v.y;
                r[4 * k + 2] = v.z; r[4 * k + 3] = v.w;
            }
#pragma unroll
            for (int e = 0; e < KS; ++e) {
                const f4 ww = w[d * KS + e];
                acc.x += ww.x * r[0 + 2 * e];
                acc.y += ww.y * r[1 + 2 * e];
                acc.z += ww.z * r[2 + 2 * e];
                acc.w += ww.w * r[3 + 2 * e];
            }
        }
        *(f4*)(outb + c * HW + obase) = acc;
    }
}

extern "C" void kernel_launch(void* const* d_in, const int* in_sizes, int n_in,
                              void* d_out, int out_size, void* d_ws, size_t ws_size,
                              hipStream_t stream) {
    const float* inp = (const float*)d_in[0];   // (4,32,512,512) fp32
    const float* par = (const float*)d_in[1];   // (4,8,512,512) fp32
    float* out = (float*)d_out;                 // (4,24,512,512) fp32

    const int total = B_ * H_ * GPR;            // 262,144 threads (4 px each)
    dim3 block(256);
    dim3 grid(total / 256);                     // 1024 blocks
    bilateral4<<<grid, block, 0, stream>>>(inp, par, out);
}